// Round 1
// baseline (7478.951 us; speedup 1.0000x reference)
//
#include <hip/hip_runtime.h>
#include <math.h>

// OptNet batched QP interior-point solver.
// B=1024 batch elements, one 256-thread block per element, everything in LDS.
// NX=64 (vars), NEQ=1 (equality), NINEQ=128 (inequalities), 5 IPM iterations.
//
// Strategy: explicit inverses instead of per-RHS triangular solves.
//   pre:  U_Q = chol(Q); V_Q = U_Q^{-1} (blocked in-place trtri); Qinv = V_Q V_Q^T
//         R = G Qinv G^T; border for NEQ=1: u11, u12; R -= u12 u12^T
//   each factorization: W = R + diag(s/z) + 1e-6 I; chol (deferred-sqrt, 1
//         barrier/column); V = U^{-1} via blocked in-place trtri (8 block cols)
//   each KKT solve: pure matvecs with Qinv, V, V^T, G (fully parallel).

#define NID 128
#define WS  129   // padded stride for W: odd => conflict-free column reads

struct SmemLayout {
  float W[NID * WS];     // 16512 floats: factor workspace / V (also Q-phase scratch)
  float R[NID * NID];    // 16384
  float Qi[64 * 64];     // 4096
  float Vd[8 * 16 * 16]; // 2048: diag-block inverses for trtri
  float x[64]; float rx[64]; float g1[64]; float dxa[64]; float dxc[64]; float t[64];
  float s[NID]; float z[NID]; float rz[NID]; float dsa[NID]; float dza[NID];
  float dsc[NID]; float dzc[NID]; float u12[NID]; float d[NID]; float H[NID]; float Y[NID];
  float scal[16];
};
static_assert(sizeof(SmemLayout) <= 163840, "LDS overflow");

enum { SC_D0 = 0, SC_D1 = 1, SC_H1 = 2, SC_U11 = 3, SC_U11I = 4, SC_RY = 5, SC_MU = 6,
       SC_ALPHA = 7, SC_MUSIG = 8, SC_Y = 9, SC_DYA = 10, SC_DYC = 11,
       SC_MINS = 12, SC_MINZ = 13 };

__device__ inline float wred_sum(float v) {
#pragma unroll
  for (int off = 32; off > 0; off >>= 1) v += __shfl_down(v, off);
  return v;
}
__device__ inline float wred_min(float v) {
#pragma unroll
  for (int off = 32; off > 0; off >>= 1) v = fminf(v, __shfl_down(v, off));
  return v;
}
__device__ inline float step_val(float v, float dv) {
  float a = -v / dv;                 // IEEE: dv==0 -> +/-inf; 0/0 -> NaN
  return (a > 0.0f) ? a : __builtin_inff();  // NaN>0 is false -> inf (matches ref)
}

// In-place upper Cholesky, deferred-sqrt form: one barrier per column.
// Update: W[i][j] -= W[k][i]*W[k][j]/W[k][k]; final pass scales row k by 1/sqrt(pivot).
// Pivot reciprocal double-buffered by parity (thread 0 owns row k+1 -> computes next pivot).
__device__ void chol_ldl(float* W, int n, int st, float* dinv2, int tid) {
  if (tid == 0) dinv2[SC_D0] = 1.0f / W[0];
  __syncthreads();
  for (int k = 0; k < n - 1; ++k) {
    const float invd = dinv2[k & 1];
    const int row = k + 1 + (tid >> 1);
    if (row < n) {
      const float m = W[k * st + row] * invd;
      for (int j = row + (tid & 1); j < n; j += 2)
        W[row * st + j] -= m * W[k * st + j];
      if (tid == 0) dinv2[(k + 1) & 1] = 1.0f / W[row * st + row];
    }
    __syncthreads();
  }
  for (int k = tid; k < n; k += 256) {
    const float rd = 1.0f / sqrtf(W[k * st + k]);
    for (int j = k; j < n; ++j) W[k * st + j] *= rd;
  }
  __syncthreads();
}

// In-place inversion of upper-triangular W (n x n, stride st), blocked by 16.
// V-leading form: V[:,Jblk] = -(V[:,0:Jb] * U[0:Jb,Jblk]) * U_JJ^{-1}, done as
// stage A: U' = U[0:Jb,Jblk] * Vd[J] (thread-per-row, in-place), stage B: the
// column sum into registers, barrier, write (plus diag block copy).
__device__ void trtri_upper(float* W, int n, int st, float* Vd, int tid) {
  const int nblk = n >> 4;
  if (tid < nblk * 16) {  // invert the 16x16 diagonal blocks (fully unrolled, registers)
    const int blk = tid >> 4, c = tid & 15;
    const float* D = W + (16 * blk) * st + 16 * blk;
    float vv[16];
#pragma unroll
    for (int i = 15; i >= 0; --i) {
      float acc = 0.0f;
      for (int k = i + 1; k < 16; ++k) acc += D[i * st + k] * vv[k];
      const float di = D[i * st + i];
      const float val = (i == c) ? (1.0f / di) : (-acc / di);
      vv[i] = (i <= c) ? val : 0.0f;
    }
#pragma unroll
    for (int i = 0; i < 16; ++i) Vd[blk * 256 + i * 16 + c] = vv[i];
  }
  __syncthreads();
  for (int J = 0; J < nblk; ++J) {
    const int Jb = 16 * J;
    if (tid < Jb) {  // stage A: rows 0..Jb-1 of column block J: U' = U * Vd[J]
      const int k = tid;
      float u[16], o[16];
#pragma unroll
      for (int jj = 0; jj < 16; ++jj) u[jj] = W[k * st + Jb + jj];
#pragma unroll
      for (int c = 0; c < 16; ++c) {
        float acc = 0.0f;
        for (int jj = 0; jj <= c; ++jj) acc += u[jj] * Vd[J * 256 + jj * 16 + c];
        o[c] = acc;
      }
#pragma unroll
      for (int c = 0; c < 16; ++c) W[k * st + Jb + c] = o[c];
    }
    __syncthreads();
    const int nOff = Jb * 16;
    const int nTot = nOff + 256;
    float rbuf[8];
    int cnt = 0;
    for (int id = tid; id < nTot; id += 256) {  // stage B compute (into registers)
      float val;
      if (id < nOff) {
        const int i = id >> 4, c = id & 15;
        float acc = 0.0f;
        for (int k = i; k < Jb; ++k) acc += W[i * st + k] * W[k * st + Jb + c];
        val = -acc;
      } else {
        val = Vd[J * 256 + (id - nOff)];  // diag block copy (has zeros below diag)
      }
      rbuf[cnt++] = val;
    }
    __syncthreads();
    cnt = 0;
    for (int id = tid; id < nTot; id += 256) {  // write phase
      int i, c;
      if (id < nOff) { i = id >> 4; c = id & 15; }
      else { const int l = id - nOff; i = Jb + (l >> 4); c = l & 15; }
      W[i * st + Jb + c] = rbuf[cnt++];
    }
    __syncthreads();
  }
}

// factor_kkt: W = R + diag(1/d) + 1e-6 I (1/d = s/z, or 1 for the initial solve),
// then chol + trtri (W ends holding V = U22^{-1}).
__device__ void factor_S(SmemLayout& sm, int init, int tid) {
  for (int idx = tid; idx < NID * NID; idx += 256) {
    const int i = idx >> 7, j = idx & 127;
    float v = sm.R[idx];
    if (i == j) v += (init ? 1.0f : (sm.s[i] / sm.z[i])) + 1e-6f;
    sm.W[i * WS + j] = v;
  }
  __syncthreads();
  chol_ldl(sm.W, NID, WS, sm.scal, tid);
  trtri_upper(sm.W, NID, WS, sm.Vd, tid);
}

// solve_kkt: all matvecs. Uses sm.W as V, sm.Qi, sm.u12, scal[SC_U11I], sm.d.
__device__ void solve_kkt(SmemLayout& sm, const float* Gb, const float* Ab,
                          int has_rx, const float* rx, const float* rs,
                          int has_rz, const float* rz, float ry,
                          float* dx, float* ds, float* wz, int wy_slot, int tid) {
  const float u11i = sm.scal[SC_U11I];
  if (has_rx) {
    if (tid < 64) {  // t = Qinv * rx
      float acc = 0.0f;
      for (int k = 0; k < 64; ++k) acc += sm.Qi[tid * 64 + k] * rx[k];
      sm.t[tid] = acc;
    }
    __syncthreads();
  }
  if (tid < 128) {  // H2 = G t + rs/d - rz
    float acc = 0.0f;
    if (has_rx) for (int k = 0; k < 64; ++k) acc += Gb[tid * 64 + k] * sm.t[k];
    if (rs) acc += rs[tid] / sm.d[tid];
    if (has_rz) acc -= rz[tid];
    sm.H[tid] = acc;
  }
  __syncthreads();
  if (tid < 64) {  // H1 = a.t - ry
    float v = has_rx ? (Ab[tid] * sm.t[tid]) : 0.0f;
    v = wred_sum(v);
    if (tid == 0) sm.scal[SC_H1] = v - ry;
  }
  __syncthreads();
  const float y1 = sm.scal[SC_H1] * u11i;
  if (tid < 128) {  // y2 = V^T (H2 - u12*y1)   (column reads, conflict-free: stride 129)
    float acc = 0.0f;
    for (int k = 0; k <= tid; ++k)
      acc += sm.W[k * WS + tid] * (sm.H[k] - sm.u12[k] * y1);
    sm.Y[tid] = acc;
  }
  __syncthreads();
  if (tid < 128) {  // w_z = -(V y2)
    float acc = 0.0f;
    for (int k = tid; k < 128; ++k) acc += sm.W[tid * WS + k] * sm.Y[k];
    wz[tid] = -acc;
  }
  __syncthreads();
  if (tid < 64) {  // w_y = -(y1 + u12 . w_z * (-1) ... ) = -(y1 + sum u12*wz)/u11
    float v = sm.u12[tid] * wz[tid] + sm.u12[tid + 64] * wz[tid + 64];
    v = wred_sum(v);
    if (tid == 0) sm.scal[wy_slot] = -(y1 + v) * u11i;
  }
  __syncthreads();
  const float wy = sm.scal[wy_slot];
  if (tid < 64) {  // g1 = -rx - G^T wz - a^T wy   (coalesced column reads of G)
    float acc = has_rx ? -rx[tid] : 0.0f;
    acc -= Ab[tid] * wy;
    for (int i = 0; i < 128; ++i) acc -= Gb[i * 64 + tid] * wz[i];
    sm.g1[tid] = acc;
  } else if (tid < 192) {  // ds = (-rs - wz)/d
    const int i = tid - 64;
    const float r = rs ? rs[i] : 0.0f;
    ds[i] = (-r - wz[i]) / sm.d[i];
  }
  __syncthreads();
  if (tid < 64) {  // dx = Qinv g1
    float acc = 0.0f;
    for (int k = 0; k < 64; ++k) acc += sm.Qi[tid * 64 + k] * sm.g1[k];
    dx[tid] = acc;
  }
  __syncthreads();
}

__global__ __launch_bounds__(256)
void optnet_kernel(const float* __restrict__ Qg, const float* __restrict__ pg,
                   const float* __restrict__ Ag, const float* __restrict__ bg,
                   const float* __restrict__ Gg, const float* __restrict__ hg,
                   float* __restrict__ outg) {
  __shared__ SmemLayout sm;
  const int bId = blockIdx.x;
  const int tid = threadIdx.x;
  const float* Qb = Qg + (size_t)bId * 4096;
  const float* pb = pg + (size_t)bId * 64;
  const float* Ab = Ag + (size_t)bId * 64;
  const float  bb = bg[bId];
  const float* Gb = Gg + (size_t)bId * 8192;
  const float* hb = hg + (size_t)bId * 128;

  // ---- pre-factor: chol(Q), V_Q = U_Q^{-1}, Qinv = V V^T (stride-65 scratch in W)
  for (int idx = tid; idx < 4096; idx += 256) {
    const int i = idx >> 6, j = idx & 63;
    sm.W[i * 65 + j] = Qb[idx];
  }
  if (tid < 128) sm.d[tid] = 1.0f;  // d0 = 1 for the initial solve
  __syncthreads();
  chol_ldl(sm.W, 64, 65, sm.scal, tid);
  trtri_upper(sm.W, 64, 65, sm.Vd, tid);
  for (int idx = tid; idx < 4096; idx += 256) {
    const int i = idx >> 6, j = idx & 63;
    const int lo = (i > j) ? i : j;
    float acc = 0.0f;
    for (int k = lo; k < 64; ++k) acc += sm.W[i * 65 + k] * sm.W[j * 65 + k];
    sm.Qi[idx] = acc;
  }
  __syncthreads();
  // ---- R = G Qinv G^T : stage G and invQ_GT in W scratch
  for (int idx = tid; idx < 8192; idx += 256) sm.W[idx] = Gb[idx];  // g(i,k)=W[i*64+k]
  __syncthreads();
  for (int idx = tid; idx < 8192; idx += 256) {  // iv(k,j) = Qinv row k . G row j
    const int k = idx >> 7, j = idx & 127;
    float acc = 0.0f;
    for (int m = 0; m < 64; ++m) acc += sm.Qi[k * 64 + m] * sm.W[j * 64 + m];
    sm.W[8192 + idx] = acc;
  }
  __syncthreads();
  for (int idx = tid; idx < 16384; idx += 256) {  // R(i,j) = g(i,:) . iv(:,j)
    const int i = idx >> 7, j = idx & 127;
    float acc = 0.0f;
    for (int k = 0; k < 64; ++k) acc += sm.W[i * 64 + k] * sm.W[8192 + k * 128 + j];
    sm.R[idx] = acc;
  }
  __syncthreads();
  // ---- equality border (NEQ=1): u11 = sqrt(a Qinv a^T), u12 = G Qinv a^T / u11
  if (tid < 64) {
    float acc = 0.0f;
    for (int m = 0; m < 64; ++m) acc += sm.Qi[tid * 64 + m] * Ab[m];
    sm.t[tid] = acc;
  }
  __syncthreads();
  if (tid < 64) {
    float v = Ab[tid] * sm.t[tid];
    v = wred_sum(v);
    if (tid == 0) { const float u = sqrtf(v); sm.scal[SC_U11] = u; sm.scal[SC_U11I] = 1.0f / u; }
  }
  __syncthreads();
  if (tid < 128) {
    float acc = 0.0f;
    for (int k = 0; k < 64; ++k) acc += sm.W[tid * 64 + k] * sm.t[k];  // G row . t
    sm.u12[tid] = acc * sm.scal[SC_U11I];
  }
  __syncthreads();
  for (int idx = tid; idx < 16384; idx += 256) {  // R -= u12 u12^T
    const int i = idx >> 7, j = idx & 127;
    sm.R[idx] -= sm.u12[i] * sm.u12[j];
  }
  if (tid < 128) sm.rz[tid] = -hb[tid];  // initial rz = -h
  __syncthreads();

  // ---- initial factor + solve (d=1): x,s,z,y
  factor_S(sm, 1, tid);
  solve_kkt(sm, Gb, Ab, 1, pb, nullptr, 1, sm.rz, -bb,
            sm.x, sm.s, sm.z, SC_Y, tid);
  // ---- clamp s, z to be >= ~1
  if (tid < 64) {
    float v = fminf(sm.s[tid], sm.s[tid + 64]);
    v = wred_min(v);
    if (tid == 0) sm.scal[SC_MINS] = v;
  } else if (tid < 128) {
    const int l = tid - 64;
    float v = fminf(sm.z[l], sm.z[l + 64]);
    v = wred_min(v);
    if (l == 0) sm.scal[SC_MINZ] = v;
  }
  __syncthreads();
  if (tid < 128) {
    const float cs = 1.0f - sm.scal[SC_MINS];
    if (cs > 1.0f) sm.s[tid] += cs;
  } else {
    const int i = tid - 128;
    const float cz = 1.0f - sm.scal[SC_MINZ];
    if (cz > 1.0f) sm.z[i] += cz;
  }
  __syncthreads();

  // ---- 5 IPM iterations
  for (int it = 0; it < 5; ++it) {
    if (tid < 64) {  // rx = G^T z + Q x + p + a^T y
      float acc = pb[tid] + Ab[tid] * sm.scal[SC_Y];
      for (int i = 0; i < 128; ++i) acc += Gb[i * 64 + tid] * sm.z[i];
      for (int j = 0; j < 64; ++j)  acc += Qb[tid * 64 + j] * sm.x[j];
      sm.rx[tid] = acc;
    } else if (tid < 192) {  // rz = G x + s - h
      const int i = tid - 64;
      float acc = sm.s[i] - hb[i];
      for (int k = 0; k < 64; ++k) acc += Gb[i * 64 + k] * sm.x[k];
      sm.rz[i] = acc;
    }
    __syncthreads();
    if (tid < 64) {  // ry = a.x - b
      float v = Ab[tid] * sm.x[tid];
      v = wred_sum(v);
      if (tid == 0) sm.scal[SC_RY] = v - bb;
    } else if (tid < 128) {  // mu = sum(s z)/128
      const int l = tid - 64;
      float v = sm.s[l] * sm.z[l] + sm.s[l + 64] * sm.z[l + 64];
      v = wred_sum(v);
      if (l == 0) sm.scal[SC_MU] = v * (1.0f / 128.0f);
    } else {  // d = z/s
      const int i = tid - 128;
      sm.d[i] = sm.z[i] / sm.s[i];
    }
    __syncthreads();
    factor_S(sm, 0, tid);
    // affine predictor (rs = z)
    solve_kkt(sm, Gb, Ab, 1, sm.rx, sm.z, 1, sm.rz, sm.scal[SC_RY],
              sm.dxa, sm.dsa, sm.dza, SC_DYA, tid);
    if (tid < 64) {  // alpha_aff
      float m = __builtin_inff();
#pragma unroll
      for (int rep = 0; rep < 2; ++rep) {
        const int i = tid + 64 * rep;
        m = fminf(m, step_val(sm.z[i], sm.dza[i]));
        m = fminf(m, step_val(sm.s[i], sm.dsa[i]));
      }
      m = wred_min(m);
      if (tid == 0) sm.scal[SC_ALPHA] = 0.999f * fminf(m, 1.0f);
    }
    __syncthreads();
    {
      const float alpha = sm.scal[SC_ALPHA];
      if (tid < 64) {  // sigma, mu_sig
        float v = 0.0f;
#pragma unroll
        for (int rep = 0; rep < 2; ++rep) {
          const int i = tid + 64 * rep;
          v += (sm.s[i] + alpha * sm.dsa[i]) * (sm.z[i] + alpha * sm.dza[i]);
        }
        v = wred_sum(v);
        if (tid == 0) {
          const float mu = sm.scal[SC_MU];
          const float r = v / (mu * 128.0f);
          sm.scal[SC_MUSIG] = -mu * r * r * r;
        }
      }
    }
    __syncthreads();
    if (tid < 128) {  // non_zero (reuse rz buffer)
      sm.rz[tid] = (sm.scal[SC_MUSIG] + sm.dsa[tid] * sm.dza[tid]) / sm.s[tid];
    }
    __syncthreads();
    // corrector (rx=0, rz=0, ry=0, rs=non_zero)
    solve_kkt(sm, Gb, Ab, 0, nullptr, sm.rz, 0, nullptr, 0.0f,
              sm.dxc, sm.dsc, sm.dzc, SC_DYC, tid);
    if (tid < 128) sm.dsa[tid] += sm.dsc[tid];
    else           sm.dza[tid - 128] += sm.dzc[tid - 128];
    __syncthreads();
    if (tid < 64) {  // alpha on combined step
      float m = __builtin_inff();
#pragma unroll
      for (int rep = 0; rep < 2; ++rep) {
        const int i = tid + 64 * rep;
        m = fminf(m, step_val(sm.z[i], sm.dza[i]));
        m = fminf(m, step_val(sm.s[i], sm.dsa[i]));
      }
      m = wred_min(m);
      if (tid == 0) sm.scal[SC_ALPHA] = 0.999f * fminf(m, 1.0f);
    } else if (tid < 128) {
      const int i = tid - 64;
      sm.dxa[i] += sm.dxc[i];
    }
    __syncthreads();
    {
      const float a2 = sm.scal[SC_ALPHA];
      if (tid < 128) sm.s[tid] += a2 * sm.dsa[tid];
      else           sm.z[tid - 128] += a2 * sm.dza[tid - 128];
    }
    __syncthreads();
    if (tid < 64) sm.x[tid] += sm.scal[SC_ALPHA] * sm.dxa[tid];
    if (tid == 64) sm.scal[SC_Y] += sm.scal[SC_ALPHA] * (sm.scal[SC_DYA] + sm.scal[SC_DYC]);
    __syncthreads();
  }
  if (tid < 64) outg[(size_t)bId * 64 + tid] = sm.x[tid];
}

extern "C" void kernel_launch(void* const* d_in, const int* in_sizes, int n_in,
                              void* d_out, int out_size, void* d_ws, size_t ws_size,
                              hipStream_t stream) {
  (void)n_in; (void)d_ws; (void)ws_size; (void)out_size;
  const float* Q = (const float*)d_in[0];
  const float* p = (const float*)d_in[1];
  const float* A = (const float*)d_in[2];
  const float* b = (const float*)d_in[3];
  const float* G = (const float*)d_in[4];
  const float* h = (const float*)d_in[5];
  const int B = in_sizes[3];  // b has one element per batch
  optnet_kernel<<<B, 256, 0, stream>>>(Q, p, A, b, G, h, (float*)d_out);
}

// Round 2
// 3353.521 us; speedup vs baseline: 2.2302x; 2.2302x over previous
//
#include <hip/hip_runtime.h>
#include <math.h>

// OptNet batched QP IPM solver. One 512-thread block per batch element.
// Round 2: register-resident Cholesky (4x8 tile/thread), packed symmetric R,
// strip-vectorized trtri, split-k matvecs, conflict-free LDS layouts.

#define NT 512
#define WS 132   // W stride: multiple of 4 -> 16B-aligned rows for float4

struct __align__(16) Smem {
  float W[128 * WS];     // 16896: factor workspace / V / prefactor scratch
  float Rp[8256];        // packed upper triangle of R (symmetric)
  float Qi[64 * 64];     // 4096: Q^{-1} (symmetric -> read col-major, conflict-free)
  float Vd[2048];        // trtri diag-block inverses / split-k partial buffers
  float pr[2][128];      // chol pivot-row double buffer
  float x[64], rxv[64], g1[64], dxa[64], dxc[64], t[64];
  float s[128], z[128], rz[128], dsa[128], dza[128], dsc[128], dzc[128];
  float u12[128], dd[128], H[128], Y[128];
  float scal[16];
};
static_assert(sizeof(Smem) <= 163840, "LDS overflow");

enum { SC_D0 = 0, SC_D1 = 1, SC_H1 = 2, SC_U11 = 3, SC_U11I = 4, SC_RY = 5, SC_MU = 6,
       SC_ALPHA = 7, SC_MUSIG = 8, SC_Y = 9, SC_DYA = 10, SC_DYC = 11,
       SC_MINS = 12, SC_MINZ = 13 };

__device__ inline float wred_sum(float v) {
#pragma unroll
  for (int off = 32; off > 0; off >>= 1) v += __shfl_down(v, off);
  return v;
}
__device__ inline float wred_min(float v) {
#pragma unroll
  for (int off = 32; off > 0; off >>= 1) v = fminf(v, __shfl_down(v, off));
  return v;
}
__device__ inline float step_val(float v, float dv) {
  float a = -v / dv;
  return (a > 0.0f) ? a : __builtin_inff();  // NaN -> inf (matches ref semantics)
}
// packed upper-triangular index: row start i*(257-i)/2
__device__ inline int pkidx(int i, int j) {
  const int mn = i < j ? i : j;
  const int mx = i + j - mn;
  return ((mn * (257 - mn)) >> 1) + (mx - mn);
}

// ---- legacy LDS chol (used only for the 64x64 Q pre-factor; cheap) ----
__device__ void chol_ldl(float* W, int n, int st, float* dinv2, int tid) {
  if (tid == 0) dinv2[SC_D0] = 1.0f / W[0];
  __syncthreads();
  for (int k = 0; k < n - 1; ++k) {
    const float invd = dinv2[k & 1];
    const int row = k + 1 + (tid >> 1);
    if (row < n) {
      const float m = W[k * st + row] * invd;
      for (int j = row + (tid & 1); j < n; j += 2)
        W[row * st + j] -= m * W[k * st + j];
      if (tid == 0) dinv2[(k + 1) & 1] = 1.0f / W[row * st + row];
    }
    __syncthreads();
  }
  for (int k = tid; k < n; k += NT) {
    const float rd = 1.0f / sqrtf(W[k * st + k]);
    for (int j = k; j < n; ++j) W[k * st + j] *= rd;
  }
  __syncthreads();
}

// ---- legacy trtri (used only for 64x64) ----
__device__ void trtri_small(float* W, int n, int st, float* Vd, int tid) {
  const int nblk = n >> 4;
  if (tid < nblk * 16) {
    const int blk = tid >> 4, c = tid & 15;
    const float* D = W + (16 * blk) * st + 16 * blk;
    float vv[16];
#pragma unroll
    for (int i = 15; i >= 0; --i) {
      float acc = 0.0f;
      for (int k = i + 1; k < 16; ++k) acc += D[i * st + k] * vv[k];
      const float di = D[i * st + i];
      const float val = (i == c) ? (1.0f / di) : (-acc / di);
      vv[i] = (i <= c) ? val : 0.0f;
    }
#pragma unroll
    for (int i = 0; i < 16; ++i) Vd[blk * 256 + i * 16 + c] = vv[i];
  }
  __syncthreads();
  for (int J = 0; J < nblk; ++J) {
    const int Jb = 16 * J;
    if (tid < Jb) {
      const int k = tid;
      float u[16], o[16];
#pragma unroll
      for (int jj = 0; jj < 16; ++jj) u[jj] = W[k * st + Jb + jj];
#pragma unroll
      for (int c = 0; c < 16; ++c) {
        float acc = 0.0f;
        for (int jj = 0; jj <= c; ++jj) acc += u[jj] * Vd[J * 256 + jj * 16 + c];
        o[c] = acc;
      }
#pragma unroll
      for (int c = 0; c < 16; ++c) W[k * st + Jb + c] = o[c];
    }
    __syncthreads();
    const int nOff = Jb * 16;
    const int nTot = nOff + 256;
    float rbuf[2];
    int cnt = 0;
    for (int id = tid; id < nTot; id += NT) {
      float val;
      if (id < nOff) {
        const int i = id >> 4, c = id & 15;
        float acc = 0.0f;
        for (int k = i; k < Jb; ++k) acc += W[i * st + k] * W[k * st + Jb + c];
        val = -acc;
      } else {
        val = Vd[J * 256 + (id - nOff)];
      }
      rbuf[cnt++] = val;
    }
    __syncthreads();
    cnt = 0;
    for (int id = tid; id < nTot; id += NT) {
      int i, c;
      if (id < nOff) { i = id >> 4; c = id & 15; }
      else { const int l = id - nOff; i = Jb + (l >> 4); c = l & 15; }
      W[i * st + Jb + c] = rbuf[cnt++];
    }
    __syncthreads();
  }
}

// ---- trtri for 128 with float4 strips (W stride WS) ----
__device__ void trtri128(Smem& sm, int tid) {
  if (tid < 128) {  // invert 16x16 diag blocks into Vd
    const int blk = tid >> 4, c = tid & 15;
    const float* D = sm.W + (blk << 4) * WS + (blk << 4);
    float vv[16];
#pragma unroll
    for (int i = 15; i >= 0; --i) {
      float acc = 0.0f;
      for (int k = i + 1; k < 16; ++k) acc += D[i * WS + k] * vv[k];
      const float di = D[i * WS + i];
      const float val = (i == c) ? (1.0f / di) : (-acc / di);
      vv[i] = (i <= c) ? val : 0.0f;
    }
#pragma unroll
    for (int i = 0; i < 16; ++i) sm.Vd[(blk << 8) + (i << 4) + c] = vv[i];
  }
  __syncthreads();
  for (int J = 0; J < 8; ++J) {
    const int Jb = J << 4;
    if (J > 0) {
      if (tid < Jb) {  // stage A: U' = U[0:Jb, Jblk] * Vd[J]
        float4* wr = (float4*)&sm.W[tid * WS + Jb];
        const float4 a0 = wr[0], a1 = wr[1], a2 = wr[2], a3 = wr[3];
        const float u[16] = {a0.x, a0.y, a0.z, a0.w, a1.x, a1.y, a1.z, a1.w,
                             a2.x, a2.y, a2.z, a2.w, a3.x, a3.y, a3.z, a3.w};
        const float* vd = sm.Vd + (J << 8);
        float o[16];
#pragma unroll
        for (int c = 0; c < 16; ++c) {
          float acc = 0.0f;
          for (int jj = 0; jj <= c; ++jj) acc += u[jj] * vd[jj * 16 + c];
          o[c] = acc;
        }
        wr[0] = make_float4(o[0], o[1], o[2], o[3]);
        wr[1] = make_float4(o[4], o[5], o[6], o[7]);
        wr[2] = make_float4(o[8], o[9], o[10], o[11]);
        wr[3] = make_float4(o[12], o[13], o[14], o[15]);
      }
      __syncthreads();
    }
    // stage B: M = -V[:,0:Jb] * U' (1-row x 4-col strips) + diag-block copy
    const int nStrip = Jb << 2;
    float acc[4] = {0.0f, 0.0f, 0.0f, 0.0f};
    int wi = 0, wc = 0;
    if (tid < nStrip) {
      wi = tid >> 2; wc = (tid & 3) << 2;
      for (int k = wi; k < Jb; ++k) {
        const float v = sm.W[wi * WS + k];
        const float4 uu = *(const float4*)&sm.W[k * WS + Jb + wc];
        acc[0] = fmaf(v, uu.x, acc[0]);
        acc[1] = fmaf(v, uu.y, acc[1]);
        acc[2] = fmaf(v, uu.z, acc[2]);
        acc[3] = fmaf(v, uu.w, acc[3]);
      }
    } else if (tid < nStrip + 64) {
      const int l = tid - nStrip;
      wi = Jb + (l >> 2); wc = (l & 3) << 2;
      const float4 uu = *(const float4*)&sm.Vd[(J << 8) + ((l >> 2) << 4) + wc];
      acc[0] = -uu.x; acc[1] = -uu.y; acc[2] = -uu.z; acc[3] = -uu.w;
    }
    __syncthreads();
    if (tid < nStrip + 64)
      *(float4*)&sm.W[wi * WS + Jb + wc] = make_float4(-acc[0], -acc[1], -acc[2], -acc[3]);
    __syncthreads();
  }
}

// ---- register-resident Cholesky of S = R + diag + eps, then V = U^{-1} ----
__device__ void factor_S(Smem& sm, int init, int tid) {
  const int tr = tid >> 4, tc = tid & 15;
  const int i0 = tr << 2, j0 = tc << 3;
  float Wt[4][8];
  float sq[4] = {0.0f, 0.0f, 0.0f, 0.0f};
#pragma unroll
  for (int m = 0; m < 4; ++m) {
    const int i = i0 + m;
#pragma unroll
    for (int c = 0; c < 8; ++c) {
      const int j = j0 + c;
      float v = sm.Rp[pkidx(i, j)];
      if (i == j) v += (init ? 1.0f : sm.s[i] / sm.z[i]) + 1e-6f;
      Wt[m][c] = v;
    }
  }
  if (tr == 0) {
#pragma unroll
    for (int c = 0; c < 8; ++c) sm.pr[0][j0 + c] = Wt[0][c];
  }
  if (tid == 0) sm.scal[SC_D0] = 1.0f / Wt[0][0];
  __syncthreads();
  for (int k = 0; k < 128; ++k) {
    const float* prb = sm.pr[k & 1];
    const float invd = sm.scal[SC_D0 + (k & 1)];
#pragma unroll
    for (int m = 0; m < 4; ++m) if (k == i0 + m) sq[m] = sqrtf(invd);
    if (i0 + 3 > k && j0 + 7 > k) {
      const float4 a = *(const float4*)&prb[i0];
      const float4 b0 = *(const float4*)&prb[j0];
      const float4 b1 = *(const float4*)&prb[j0 + 4];
      float pi[4] = {a.x, a.y, a.z, a.w};
      float pj[8] = {b0.x, b0.y, b0.z, b0.w, b1.x, b1.y, b1.z, b1.w};
      float um[4];
#pragma unroll
      for (int m = 0; m < 4; ++m) um[m] = (i0 + m > k) ? pi[m] * invd : 0.0f;
#pragma unroll
      for (int c = 0; c < 8; ++c) pj[c] = (j0 + c > k) ? pj[c] : 0.0f;
#pragma unroll
      for (int m = 0; m < 4; ++m)
#pragma unroll
        for (int c = 0; c < 8; ++c) Wt[m][c] = fmaf(-um[m], pj[c], Wt[m][c]);
    }
    if (k < 127) {
      const int nr = k + 1;
      if ((nr >> 2) == tr) {
        float* prn = sm.pr[nr & 1];
        float dval = 0.0f;
#pragma unroll
        for (int m = 0; m < 4; ++m) if (nr == i0 + m) {
#pragma unroll
          for (int c = 0; c < 8; ++c) {
            prn[j0 + c] = Wt[m][c];
            if (j0 + c == nr) dval = Wt[m][c];
          }
        }
        if ((nr >> 3) == tc) sm.scal[SC_D0 + (nr & 1)] = 1.0f / dval;
      }
    }
    __syncthreads();
  }
  // write scaled U to W
#pragma unroll
  for (int m = 0; m < 4; ++m) {
    *(float4*)&sm.W[(i0 + m) * WS + j0] =
        make_float4(Wt[m][0] * sq[m], Wt[m][1] * sq[m], Wt[m][2] * sq[m], Wt[m][3] * sq[m]);
    *(float4*)&sm.W[(i0 + m) * WS + j0 + 4] =
        make_float4(Wt[m][4] * sq[m], Wt[m][5] * sq[m], Wt[m][6] * sq[m], Wt[m][7] * sq[m]);
  }
  __syncthreads();
  trtri128(sm, tid);
}

// ---- KKT solve: all matvecs, split-k x4, conflict-free / coalesced ----
__device__ void solve_kkt(Smem& sm, const float* Gb, const float* Ab,
                          int has_rx, const float* rx, const float* rs,
                          int has_rz, const float* rz, float ry,
                          float* dx, float* ds, float* wz, int wy_slot, int tid) {
  const float u11i = sm.scal[SC_U11I];
  if (has_rx) {  // t = Qinv rx  (Qi symmetric: column reads = conflict-free)
    if (tid < 256) {
      const int o = tid & 63, p = tid >> 6;
      float acc = 0.0f;
      for (int m = (p << 4); m < (p << 4) + 16; ++m) acc += sm.Qi[(m << 6) + o] * rx[m];
      sm.Vd[(p << 6) + o] = acc;
    }
    __syncthreads();
    if (tid < 64) sm.t[tid] = sm.Vd[tid] + sm.Vd[64 + tid] + sm.Vd[128 + tid] + sm.Vd[192 + tid];
    __syncthreads();
  }
  {  // H = G t + rs/d - rz  (coalesced float4 row dots, 4-lane groups)
    const int i = tid >> 2, q = tid & 3;
    float acc = 0.0f;
    if (has_rx) {
      const float* gr = Gb + (i << 6) + (q << 4);
      for (int kk = 0; kk < 16; kk += 4) {
        const float4 g4 = *(const float4*)(gr + kk);
        const float4 t4 = *(const float4*)&sm.t[(q << 4) + kk];
        acc += g4.x * t4.x + g4.y * t4.y + g4.z * t4.z + g4.w * t4.w;
      }
    }
    acc += __shfl_down(acc, 2);
    acc += __shfl_down(acc, 1);
    if (q == 0) {
      if (rs) acc += rs[i] / sm.dd[i];
      if (has_rz) acc -= rz[i];
      sm.H[i] = acc;
    }
  }
  __syncthreads();
  if (tid < 64) {  // H1 = a.t - ry
    float v = has_rx ? (Ab[tid] * sm.t[tid]) : 0.0f;
    v = wred_sum(v);
    if (tid == 0) sm.scal[SC_H1] = v - ry;
  }
  __syncthreads();
  const float y1 = sm.scal[SC_H1] * u11i;
  if (tid < 128) sm.H[tid] -= sm.u12[tid] * y1;
  __syncthreads();
  {  // Y = V^T H  (4-way split-k)
    const int o = tid & 127, p = tid >> 7;
    const int k0 = p << 5;
    int k1 = k0 + 32; if (k1 > o + 1) k1 = o + 1;
    float acc = 0.0f;
    for (int k = k0; k < k1; ++k) acc += sm.W[k * WS + o] * sm.H[k];
    sm.Vd[(p << 7) + o] = acc;
  }
  __syncthreads();
  if (tid < 128) sm.Y[tid] = sm.Vd[tid] + sm.Vd[128 + tid] + sm.Vd[256 + tid] + sm.Vd[384 + tid];
  __syncthreads();
  {  // wz = -(V Y)  (4-way split-k)
    const int o = tid & 127, p = tid >> 7;
    int k0 = p << 5; if (k0 < o) k0 = o;
    const int k1 = (p << 5) + 32;
    float acc = 0.0f;
    for (int k = k0; k < k1; ++k) acc += sm.W[o * WS + k] * sm.Y[k];
    sm.Vd[512 + (p << 7) + o] = acc;
  }
  __syncthreads();
  if (tid < 128)
    wz[tid] = -(sm.Vd[512 + tid] + sm.Vd[640 + tid] + sm.Vd[768 + tid] + sm.Vd[896 + tid]);
  __syncthreads();
  if (tid < 64) {  // w_y
    float v = sm.u12[tid] * wz[tid] + sm.u12[tid + 64] * wz[tid + 64];
    v = wred_sum(v);
    if (tid == 0) sm.scal[wy_slot] = -(y1 + v) * u11i;
  }
  __syncthreads();
  const float wy = sm.scal[wy_slot];
  if (tid < 256) {  // g1 partials: -G^T wz (coalesced column reads)
    const int o = tid & 63, p = tid >> 6;
    float acc = 0.0f;
    for (int i = (p << 5); i < (p << 5) + 32; ++i) acc -= Gb[(i << 6) + o] * wz[i];
    sm.Vd[(p << 6) + o] = acc;
  } else if (tid < 384) {  // ds = (-rs - wz)/d
    const int i = tid - 256;
    const float r = rs ? rs[i] : 0.0f;
    ds[i] = (-r - wz[i]) / sm.dd[i];
  }
  __syncthreads();
  if (tid < 64) {
    float acc = sm.Vd[tid] + sm.Vd[64 + tid] + sm.Vd[128 + tid] + sm.Vd[192 + tid] - Ab[tid] * wy;
    if (has_rx) acc -= rx[tid];
    sm.g1[tid] = acc;
  }
  __syncthreads();
  if (tid < 256) {  // dx = Qinv g1
    const int o = tid & 63, p = tid >> 6;
    float acc = 0.0f;
    for (int m = (p << 4); m < (p << 4) + 16; ++m) acc += sm.Qi[(m << 6) + o] * sm.g1[m];
    sm.Vd[(p << 6) + o] = acc;
  }
  __syncthreads();
  if (tid < 64) dx[tid] = sm.Vd[tid] + sm.Vd[64 + tid] + sm.Vd[128 + tid] + sm.Vd[192 + tid];
  __syncthreads();
}

__global__ __launch_bounds__(NT, 2)
void optnet_kernel(const float* __restrict__ Qg, const float* __restrict__ pg,
                   const float* __restrict__ Ag, const float* __restrict__ bg,
                   const float* __restrict__ Gg, const float* __restrict__ hg,
                   float* __restrict__ outg) {
  __shared__ Smem sm;
  const int bId = blockIdx.x;
  const int tid = threadIdx.x;
  const float* Qb = Qg + (size_t)bId * 4096;
  const float* pb = pg + (size_t)bId * 64;
  const float* Ab = Ag + (size_t)bId * 64;
  const float  bb = bg[bId];
  const float* Gb = Gg + (size_t)bId * 8192;
  const float* hb = hg + (size_t)bId * 128;

  // ---- pre-factor Q: chol + trtri at stride 68, Qinv = V V^T
  for (int idx = tid; idx < 4096; idx += NT) {
    const int i = idx >> 6, j = idx & 63;
    sm.W[i * 68 + j] = Qb[idx];
  }
  if (tid < 128) sm.dd[tid] = 1.0f;
  __syncthreads();
  chol_ldl(sm.W, 64, 68, sm.scal, tid);
  trtri_small(sm.W, 64, 68, sm.Vd, tid);
  for (int idx = tid; idx < 4096; idx += NT) {
    const int i = idx >> 6, j = idx & 63;
    const int lo = (i > j) ? i : j;
    float acc = 0.0f;
    for (int k = lo; k < 64; ++k) acc += sm.W[i * 68 + k] * sm.W[j * 68 + k];
    sm.Qi[idx] = acc;
  }
  __syncthreads();
  // ---- stage G (stride 65, conflict-free row dots), iv = Qinv G^T at W+8320
  for (int idx = tid; idx < 8192; idx += NT) {
    const int i = idx >> 6, j = idx & 63;
    sm.W[i * 65 + j] = Gb[idx];
  }
  __syncthreads();
  for (int idx = tid; idx < 8192; idx += NT) {
    const int m = idx >> 7, j = idx & 127;
    float acc = 0.0f;
    for (int k = 0; k < 64; ++k) acc += sm.Qi[(m << 6) + k] * sm.W[j * 65 + k];
    sm.W[8320 + (m << 7) + j] = acc;
  }
  __syncthreads();
  // ---- R = G Qinv G^T, upper triangle, register-tiled (4x8 per thread)
  float racc[4][8] = {};
  {
    const int tr = tid >> 4, tc = tid & 15;
    const int i0 = tr << 2, j0 = tc << 3;
    for (int m = 0; m < 64; ++m) {
      float gv[4];
#pragma unroll
      for (int mm = 0; mm < 4; ++mm) gv[mm] = sm.W[(i0 + mm) * 65 + m];
      const float4 v0 = *(const float4*)&sm.W[8320 + (m << 7) + j0];
      const float4 v1 = *(const float4*)&sm.W[8320 + (m << 7) + j0 + 4];
      const float vj[8] = {v0.x, v0.y, v0.z, v0.w, v1.x, v1.y, v1.z, v1.w};
#pragma unroll
      for (int mm = 0; mm < 4; ++mm)
#pragma unroll
        for (int cc = 0; cc < 8; ++cc) racc[mm][cc] = fmaf(gv[mm], vj[cc], racc[mm][cc]);
    }
  }
  // ---- equality border: t = Qinv a, u11, u12
  if (tid < 64) {
    float acc = 0.0f;
    for (int k = 0; k < 64; ++k) acc += sm.Qi[(k << 6) + tid] * Ab[k];
    sm.t[tid] = acc;
  }
  __syncthreads();
  if (tid < 64) {
    float v = Ab[tid] * sm.t[tid];
    v = wred_sum(v);
    if (tid == 0) { const float u = sqrtf(v); sm.scal[SC_U11] = u; sm.scal[SC_U11I] = 1.0f / u; }
  }
  __syncthreads();
  if (tid < 128) {
    float acc = 0.0f;
    for (int k = 0; k < 64; ++k) acc += sm.W[tid * 65 + k] * sm.t[k];
    sm.u12[tid] = acc * sm.scal[SC_U11I];
  }
  if (tid < 128) sm.rz[tid] = -hb[tid];
  __syncthreads();
  // ---- write packed R -= u12 u12^T (fused with R build, upper only)
  {
    const int tr = tid >> 4, tc = tid & 15;
    const int i0 = tr << 2, j0 = tc << 3;
#pragma unroll
    for (int mm = 0; mm < 4; ++mm) {
      const int i = i0 + mm;
      const float ui = sm.u12[i];
#pragma unroll
      for (int cc = 0; cc < 8; ++cc) {
        const int j = j0 + cc;
        if (i <= j) sm.Rp[pkidx(i, j)] = racc[mm][cc] - ui * sm.u12[j];
      }
    }
  }
  __syncthreads();

  // ---- initial factor + solve (d=1)
  factor_S(sm, 1, tid);
  solve_kkt(sm, Gb, Ab, 1, pb, nullptr, 1, sm.rz, -bb, sm.x, sm.s, sm.z, SC_Y, tid);
  if (tid < 64) {
    float v = fminf(sm.s[tid], sm.s[tid + 64]);
    v = wred_min(v);
    if (tid == 0) sm.scal[SC_MINS] = v;
  } else if (tid < 128) {
    const int l = tid - 64;
    float v = fminf(sm.z[l], sm.z[l + 64]);
    v = wred_min(v);
    if (l == 0) sm.scal[SC_MINZ] = v;
  }
  __syncthreads();
  if (tid < 128) {
    const float cs = 1.0f - sm.scal[SC_MINS];
    if (cs > 1.0f) sm.s[tid] += cs;
  } else if (tid < 256) {
    const int i = tid - 128;
    const float cz = 1.0f - sm.scal[SC_MINZ];
    if (cz > 1.0f) sm.z[i] += cz;
  }
  __syncthreads();

  // ---- 5 IPM iterations
  for (int it = 0; it < 5; ++it) {
    if (tid < 256) {  // rx partials: G^T z + Q x (Q symmetric -> coalesced)
      const int o = tid & 63, pq = tid >> 6;
      float acc = 0.0f;
      for (int i = (pq << 5); i < (pq << 5) + 32; ++i) acc += Gb[(i << 6) + o] * sm.z[i];
      for (int k = (pq << 4); k < (pq << 4) + 16; ++k) acc += Qb[(k << 6) + o] * sm.x[k];
      sm.Vd[(pq << 6) + o] = acc;
    } else {  // rz = G x + s - h (coalesced row dots, 2-lane groups)
      const int l = tid - 256, i = l >> 1, q = l & 1;
      const float* gr = Gb + (i << 6) + (q << 5);
      float acc = 0.0f;
      for (int kk = 0; kk < 32; kk += 4) {
        const float4 g4 = *(const float4*)(gr + kk);
        const float4 x4 = *(const float4*)&sm.x[(q << 5) + kk];
        acc += g4.x * x4.x + g4.y * x4.y + g4.z * x4.z + g4.w * x4.w;
      }
      acc += __shfl_down(acc, 1);
      if (q == 0) sm.rz[i] = acc + sm.s[i] - hb[i];
    }
    __syncthreads();
    if (tid < 64)
      sm.rxv[tid] = pb[tid] + Ab[tid] * sm.scal[SC_Y]
                  + sm.Vd[tid] + sm.Vd[64 + tid] + sm.Vd[128 + tid] + sm.Vd[192 + tid];
    __syncthreads();
    if (tid < 64) {  // ry
      float v = Ab[tid] * sm.x[tid];
      v = wred_sum(v);
      if (tid == 0) sm.scal[SC_RY] = v - bb;
    } else if (tid < 128) {  // mu
      const int l = tid - 64;
      float v = sm.s[l] * sm.z[l] + sm.s[l + 64] * sm.z[l + 64];
      v = wred_sum(v);
      if (l == 0) sm.scal[SC_MU] = v * (1.0f / 128.0f);
    } else if (tid < 256) {
      const int i = tid - 128;
      sm.dd[i] = sm.z[i] / sm.s[i];
    }
    __syncthreads();
    factor_S(sm, 0, tid);
    solve_kkt(sm, Gb, Ab, 1, sm.rxv, sm.z, 1, sm.rz, sm.scal[SC_RY],
              sm.dxa, sm.dsa, sm.dza, SC_DYA, tid);
    if (tid < 64) {  // alpha_aff
      float m = __builtin_inff();
#pragma unroll
      for (int rep = 0; rep < 2; ++rep) {
        const int i = tid + 64 * rep;
        m = fminf(m, step_val(sm.z[i], sm.dza[i]));
        m = fminf(m, step_val(sm.s[i], sm.dsa[i]));
      }
      m = wred_min(m);
      if (tid == 0) sm.scal[SC_ALPHA] = 0.999f * fminf(m, 1.0f);
    }
    __syncthreads();
    {
      const float alpha = sm.scal[SC_ALPHA];
      if (tid < 64) {  // sigma -> mu_sig
        float v = 0.0f;
#pragma unroll
        for (int rep = 0; rep < 2; ++rep) {
          const int i = tid + 64 * rep;
          v += (sm.s[i] + alpha * sm.dsa[i]) * (sm.z[i] + alpha * sm.dza[i]);
        }
        v = wred_sum(v);
        if (tid == 0) {
          const float mu = sm.scal[SC_MU];
          const float r = v / (mu * 128.0f);
          sm.scal[SC_MUSIG] = -mu * r * r * r;
        }
      }
    }
    __syncthreads();
    if (tid < 128)
      sm.rz[tid] = (sm.scal[SC_MUSIG] + sm.dsa[tid] * sm.dza[tid]) / sm.s[tid];
    __syncthreads();
    solve_kkt(sm, Gb, Ab, 0, nullptr, sm.rz, 0, nullptr, 0.0f,
              sm.dxc, sm.dsc, sm.dzc, SC_DYC, tid);
    if (tid < 128) sm.dsa[tid] += sm.dsc[tid];
    else if (tid < 256) sm.dza[tid - 128] += sm.dzc[tid - 128];
    __syncthreads();
    if (tid < 64) {  // alpha on combined step
      float m = __builtin_inff();
#pragma unroll
      for (int rep = 0; rep < 2; ++rep) {
        const int i = tid + 64 * rep;
        m = fminf(m, step_val(sm.z[i], sm.dza[i]));
        m = fminf(m, step_val(sm.s[i], sm.dsa[i]));
      }
      m = wred_min(m);
      if (tid == 0) sm.scal[SC_ALPHA] = 0.999f * fminf(m, 1.0f);
    } else if (tid < 128) {
      sm.dxa[tid - 64] += sm.dxc[tid - 64];
    }
    __syncthreads();
    {
      const float a2 = sm.scal[SC_ALPHA];
      if (tid < 128) sm.s[tid] += a2 * sm.dsa[tid];
      else if (tid < 256) sm.z[tid - 128] += a2 * sm.dza[tid - 128];
    }
    __syncthreads();
    if (tid < 64) sm.x[tid] += sm.scal[SC_ALPHA] * sm.dxa[tid];
    if (tid == 64) sm.scal[SC_Y] += sm.scal[SC_ALPHA] * (sm.scal[SC_DYA] + sm.scal[SC_DYC]);
    __syncthreads();
  }
  if (tid < 64) outg[((size_t)bId << 6) + tid] = sm.x[tid];
}

extern "C" void kernel_launch(void* const* d_in, const int* in_sizes, int n_in,
                              void* d_out, int out_size, void* d_ws, size_t ws_size,
                              hipStream_t stream) {
  (void)n_in; (void)d_ws; (void)ws_size; (void)out_size;
  const float* Q = (const float*)d_in[0];
  const float* p = (const float*)d_in[1];
  const float* A = (const float*)d_in[2];
  const float* b = (const float*)d_in[3];
  const float* G = (const float*)d_in[4];
  const float* h = (const float*)d_in[5];
  const int B = in_sizes[3];  // b has one element per batch
  optnet_kernel<<<B, NT, 0, stream>>>(Q, p, A, b, G, h, (float*)d_out);
}